// Round 5
// baseline (329.814 us; speedup 1.0000x reference)
//
#include <hip/hip_runtime.h>
#include <hip/hip_cooperative_groups.h>

namespace cg = cooperative_groups;

// ---------- types ----------
using bf16x8 = __attribute__((ext_vector_type(8))) __bf16;
using f32x4  = __attribute__((ext_vector_type(4))) float;
using f32x2  = __attribute__((ext_vector_type(2))) float;
using us8    = __attribute__((ext_vector_type(8))) unsigned short;

#define TWO_LOG2E 2.8853900817779268f
#define LOG2E 1.4426950408889634f

__device__ __forceinline__ unsigned short f2bf(float x) {
  unsigned int u = __float_as_uint(x);
  u = (u + 0x7fffu + ((u >> 16) & 1u)) >> 16;   // RNE
  return (unsigned short)u;
}
__device__ __forceinline__ float bf2f(unsigned short h) {
  return __uint_as_float(((unsigned int)h) << 16);
}
__device__ __forceinline__ f32x2 pk_fma(f32x2 a, f32x2 b, f32x2 c) {
  return __builtin_elementwise_fma(a, b, c);
}

// ---------- single cooperative dispatch, 4 phases ----------
// P0: transpose+cast W/V + wv2/Wsum/worklist prologue (1152 tile jobs)
// P1: projection GEMM + e^{2x} epilogue (1024 jobs)
// P2: scores work-steal over VALID 32q x 32k tiles (fine-grained balance)
// P3: fused masked-softmax + AV (512 uniform jobs: b, n-half, m-tile)
// grid.sync() (driver-optimized) replaces 3 kernel-boundary drains (~22us each).
__global__ __launch_bounds__(256, 2) void mega_kernel(
    const float* __restrict__ q, const float* __restrict__ kk,
    const float* __restrict__ vals, const float* __restrict__ wv,
    const int* __restrict__ vlens,
    const float* __restrict__ Wq, const float* __restrict__ Wk,
    unsigned short* __restrict__ wt_hi, unsigned short* __restrict__ wt_lo,
    unsigned short* __restrict__ vt_hi, unsigned short* __restrict__ vt_lo,
    float* __restrict__ wv2, float* __restrict__ Wsum, int* __restrict__ cum,
    int* __restrict__ ctr, float* __restrict__ Rq, float* __restrict__ RkT,
    float* __restrict__ sc, float* __restrict__ out) {
  __shared__ __align__(16) char smem[18448];
  cg::grid_group grid = cg::this_grid();
  const int nblk = gridDim.x;
  const int t = threadIdx.x;

  // ================= P0: W/V transpose+cast + prologue =================
  if (blockIdx.x == 0) {
    wv2[t] = -2.0f * wv[t];                       // folded weight for scores
    if (t < 64) {
      float s = wv[t] + wv[t + 64] + wv[t + 128] + wv[t + 192];
#pragma unroll
      for (int off = 1; off < 64; off <<= 1) s += __shfl_xor(s, off, 64);
      if (t == 0) Wsum[0] = s;
    }
    if (t == 0) {                                 // scores work list + steal ctr
      ctr[0] = 0;
      int c = 0;
      for (int b = 0; b < 16; ++b) {
        cum[b] = c;
        c += ((vlens[b] + 31) >> 5) << 3;         // ktiles(b) * 8 q-tiles
      }
      cum[16] = c;
    }
  }
  {
    float (*tile)[33] = (float(*)[33])smem;
    int r = t >> 3, c4 = (t & 7) << 2;
    for (int j = blockIdx.x; j < 1152; j += nblk) {
      __syncthreads();                       // prev iter's tile reads done
      int m = j >> 6;                        // matrix 0..17
      int ts = j & 63;
      int R0 = (ts >> 3) << 5, C0 = (ts & 7) << 5;
      const float* src = (m == 0) ? Wq : (m == 1) ? Wk : (vals + ((m - 2) << 16));
      float4 v = *(const float4*)(src + (R0 + r) * 256 + C0 + c4);
      tile[r][c4] = v.x; tile[r][c4 + 1] = v.y;
      tile[r][c4 + 2] = v.z; tile[r][c4 + 3] = v.w;
      __syncthreads();
      float o0 = tile[c4 + 0][r], o1 = tile[c4 + 1][r];
      float o2 = tile[c4 + 2][r], o3 = tile[c4 + 3][r];
      unsigned short h0 = f2bf(o0), h1 = f2bf(o1), h2 = f2bf(o2), h3 = f2bf(o3);
      int base = ((m < 2) ? (m << 16) : ((m - 2) << 16)) + (C0 + r) * 256 + R0 + c4;
      unsigned short* dh = (m < 2) ? wt_hi : vt_hi;
      unsigned short* dl = (m < 2) ? wt_lo : vt_lo;
      *(ushort4*)(dh + base) = make_ushort4(h0, h1, h2, h3);
      *(ushort4*)(dl + base) = make_ushort4(f2bf(o0 - bf2f(h0)), f2bf(o1 - bf2f(h1)),
                                            f2bf(o2 - bf2f(h2)), f2bf(o3 - bf2f(h3)));
    }
  }
  grid.sync();

  // ================= P1: projection GEMM + e^{2x} =================
  for (int j = blockIdx.x; j < 1024; j += nblk) {
    int wave = t >> 6, lane = t & 63;
    int mt = ((j & 255) << 1) + (wave & 1);    // m-tile 0..511
    int m0 = mt << 4;
    int g = mt >> 8;                           // 0: q rows / W_q, 1: k rows / W_k
    if (g) {                                   // key rows >= valid_len never read
      int bb = (m0 >> 8) & 15;
      if ((m0 & 255) >= vlens[bb]) continue;   // wave-uniform skip (no syncs)
    }
    int r = lane & 15, qd = lane >> 4;
    int row = m0 + r;
    const float* A = (g == 0) ? (q + row * 256) : (kk + (row - 4096) * 256);
    int nbase = ((j >> 8) << 6) + ((wave >> 1) << 5);
    int boff0 = (g << 16) + (nbase + r) * 256 + qd * 8;
    int boff1 = boff0 + (16 << 8);             // second n-tile (+16 rows)
    f32x4 acc0 = {0.f, 0.f, 0.f, 0.f}, acc1 = {0.f, 0.f, 0.f, 0.f};
#pragma unroll
    for (int kh = 0; kh < 2; ++kh) {
      bf16x8 ah[4], al[4];
#pragma unroll
      for (int s = 0; s < 4; ++s) {
        const float* p = A + qd * 8 + (kh * 4 + s) * 32;
        float4 f0 = *(const float4*)p;
        float4 f1 = *(const float4*)(p + 4);
        float fv[8] = {f0.x, f0.y, f0.z, f0.w, f1.x, f1.y, f1.z, f1.w};
#pragma unroll
        for (int jj = 0; jj < 8; ++jj) {
          __bf16 h = (__bf16)fv[jj];
          ah[s][jj] = h;
          al[s][jj] = (__bf16)(fv[jj] - (float)h);
        }
      }
#pragma unroll
      for (int s = 0; s < 4; ++s) {
        int off = (kh * 4 + s) * 32;
        bf16x8 bh0 = *(const bf16x8*)(wt_hi + boff0 + off);
        bf16x8 bl0 = *(const bf16x8*)(wt_lo + boff0 + off);
        acc0 = __builtin_amdgcn_mfma_f32_16x16x32_bf16(ah[s], bh0, acc0, 0, 0, 0);
        acc0 = __builtin_amdgcn_mfma_f32_16x16x32_bf16(ah[s], bl0, acc0, 0, 0, 0);
        acc0 = __builtin_amdgcn_mfma_f32_16x16x32_bf16(al[s], bh0, acc0, 0, 0, 0);
        bf16x8 bh1 = *(const bf16x8*)(wt_hi + boff1 + off);
        bf16x8 bl1 = *(const bf16x8*)(wt_lo + boff1 + off);
        acc1 = __builtin_amdgcn_mfma_f32_16x16x32_bf16(ah[s], bh1, acc1, 0, 0, 0);
        acc1 = __builtin_amdgcn_mfma_f32_16x16x32_bf16(ah[s], bl1, acc1, 0, 0, 0);
        acc1 = __builtin_amdgcn_mfma_f32_16x16x32_bf16(al[s], bh1, acc1, 0, 0, 0);
      }
    }
#pragma unroll
    for (int tI = 0; tI < 2; ++tI) {
      f32x4 acc = tI ? acc1 : acc0;
      int n0 = nbase + (tI << 4);
      f32x4 ex;
#pragma unroll
      for (int i = 0; i < 4; ++i) {
        float l = acc[i] * TWO_LOG2E;               // log2(e^{2x})
        l = fminf(fmaxf(l, -27.f), 27.f);
        ex[i] = __builtin_amdgcn_exp2f(l);
      }
      if (g == 0) {
#pragma unroll
        for (int i = 0; i < 4; ++i)
          Rq[(m0 + qd * 4 + i) * 256 + n0 + r] = ex[i];
      } else {
        int b = (m0 >> 8) & 15;
        int kloc = (m0 & 255) + qd * 4;             // contiguous in i
        *(f32x4*)(RkT + (b << 16) + (n0 + r) * 256 + kloc) = ex;
      }
    }
  }
  grid.sync();

  // ================= P2: scores work-steal (32q x 32k valid tiles) ========
  {
    float* rqs = (float*)smem;                     // [32][76]
    float* kT  = (float*)(smem + 9728);            // [64][34]
    int* s_item = (int*)(smem + 18432);
    const int tq = t >> 4, tk = t & 15;
    const int sr = t >> 3, shb = (t & 7) << 3;     // q staging
    const int hrow = t >> 2, kq = (t & 3) << 3;    // k staging
    const int total = cum[16];
    const float ws = Wsum[0];

    for (;;) {
      __syncthreads();                    // fences prev item's LDS use + s_item
      if (t == 0) s_item[0] = atomicAdd(ctr, 1);
      __syncthreads();
      const int w = s_item[0];
      if (w >= total) break;              // uniform exit
      int b = 0;
      while (cum[b + 1] <= w) ++b;        // <=16 uniform cached loads
      const int local = w - cum[b];
      const int k0 = (local >> 3) << 5;
      const int q0 = (local & 7) << 5;
      const int qrow = (b << 8) + q0;
      f32x2 a0 = {0.f, 0.f}, a1 = {0.f, 0.f};

      for (int hc = 0; hc < 4; ++hc) {
        if (hc) __syncthreads();
        const float* gq = Rq + (qrow + sr) * 256 + (hc << 6) + shb;
        *(float4*)(rqs + sr * 76 + shb)     = *(const float4*)gq;
        *(float4*)(rqs + sr * 76 + shb + 4) = *(const float4*)(gq + 4);
        const float* gk = RkT + (b << 16) + ((hc << 6) + hrow) * 256 + k0 + kq;
        *(float4*)(kT + hrow * 34 + kq)     = *(const float4*)gk;
        *(float4*)(kT + hrow * 34 + kq + 4) = *(const float4*)(gk + 4);
        __syncthreads();
#pragma unroll 2
        for (int h = 0; h < 64; h += 4) {
          f32x4 qa = *(const f32x4*)(rqs + tq * 76 + h);
          f32x4 qb = *(const f32x4*)(rqs + (tq + 16) * 76 + h);
          f32x4 wm = *(const f32x4*)(wv2 + (hc << 6) + h);
#pragma unroll
          for (int jj = 0; jj < 4; ++jj) {
            f32x2 rk = *(const f32x2*)(kT + (h + jj) * 34 + (tk << 1));
            f32x2 wj = (f32x2)(wm[jj]);
            f32x2 d0 = pk_fma(rk, (f32x2)(qa[jj]), (f32x2)(1.0f));
            f32x2 d1 = pk_fma(rk, (f32x2)(qb[jj]), (f32x2)(1.0f));
            f32x2 r0, r1;
            r0.x = __uint_as_float(0x7EF311C3u - __float_as_uint(d0.x));
            r0.y = __uint_as_float(0x7EF311C3u - __float_as_uint(d0.y));
            r1.x = __uint_as_float(0x7EF311C3u - __float_as_uint(d1.x));
            r1.y = __uint_as_float(0x7EF311C3u - __float_as_uint(d1.y));
            r0 = r0 * pk_fma(-d0, r0, (f32x2)(2.0f));   // 1 Newton
            r1 = r1 * pk_fma(-d1, r1, (f32x2)(2.0f));
            a0 = pk_fma(r0, wj, a0);
            a1 = pk_fma(r1, wj, a1);
          }
        }
      }
      a0 += (f32x2)(ws);
      a1 += (f32x2)(ws);
      *(f32x2*)(sc + ((qrow + tq) << 8) + k0 + (tk << 1)) = a0;
      *(f32x2*)(sc + ((qrow + tq + 16) << 8) + k0 + (tk << 1)) = a1;
    }
  }
  grid.sync();

  // ================= P3: masked softmax + AV (512 uniform jobs) =========
  for (int j = blockIdx.x; j < 512; j += nblk) {
    __syncthreads();                       // prev iter's athi reads done
    unsigned short* athi = (unsigned short*)smem;   // [16][264]
    const int wave = t >> 6, lane = t & 63;
    const int b = j & 15;                  // b fastest: mixes vl across CUs
    const int nh = (j >> 4) & 1;           // n-half 0/1
    const int m0 = (j >> 5) << 4;
    const int vl = vlens[b];

    {  // softmax: wave handles rows wave*4 + (lane&3); lane holds 16 cols
      int row = (wave << 2) + (lane & 3);
      int c0 = (lane >> 2) << 4;
      const float* srow = sc + ((b << 8) + m0 + row) * 256 + c0;
      float4 x0 = *(const float4*)(srow);
      float4 x1 = *(const float4*)(srow + 4);
      float4 x2 = *(const float4*)(srow + 8);
      float4 x3 = *(const float4*)(srow + 12);
      float p[16] = {x0.x, x0.y, x0.z, x0.w, x1.x, x1.y, x1.z, x1.w,
                     x2.x, x2.y, x2.z, x2.w, x3.x, x3.y, x3.z, x3.w};
#pragma unroll
      for (int i = 0; i < 16; ++i)
        if (c0 + i >= vl) p[i] = -1e6f;
      float mx = p[0];
#pragma unroll
      for (int i = 1; i < 16; ++i) mx = fmaxf(mx, p[i]);
#pragma unroll
      for (int off = 4; off <= 32; off <<= 1) mx = fmaxf(mx, __shfl_xor(mx, off, 64));
      float sm = 0.f;
#pragma unroll
      for (int i = 0; i < 16; ++i) {
        p[i] = __builtin_amdgcn_exp2f((p[i] - mx) * LOG2E);   // masked -> 0
        sm += p[i];
      }
#pragma unroll
      for (int off = 4; off <= 32; off <<= 1) sm += __shfl_xor(sm, off, 64);
      float rs = __builtin_amdgcn_rcpf(sm);
      us8 vh[2];
#pragma unroll
      for (int i = 0; i < 16; ++i) vh[i >> 3][i & 7] = f2bf(p[i] * rs);
      *(us8*)(athi + row * 264 + c0)     = vh[0];
      *(us8*)(athi + row * 264 + c0 + 8) = vh[1];
    }
    __syncthreads();

    // AV: wave covers 2 n-tiles in its 128-col half; K clamped to valid
    const int r = lane & 15, qd = lane >> 4;
    const int smax = (vl + 31) >> 5;
#pragma unroll
    for (int tI = 0; tI < 2; ++tI) {
      int n0 = (nh << 7) + (wave << 5) + (tI << 4);
      int boff = (b << 16) + (n0 + r) * 256 + qd * 8;
      f32x4 acc = {0.f, 0.f, 0.f, 0.f};
      for (int s = 0; s < smax; ++s) {
        bf16x8 pa = *(const bf16x8*)(athi + r * 264 + qd * 8 + s * 32);
        bf16x8 bh = *(const bf16x8*)(vt_hi + boff + s * 32);
        bf16x8 bl = *(const bf16x8*)(vt_lo + boff + s * 32);
        acc = __builtin_amdgcn_mfma_f32_16x16x32_bf16(pa, bh, acc, 0, 0, 0);
        acc = __builtin_amdgcn_mfma_f32_16x16x32_bf16(pa, bl, acc, 0, 0, 0);
      }
#pragma unroll
      for (int i = 0; i < 4; ++i)
        out[(b << 16) + (m0 + qd * 4 + i) * 256 + n0 + r] = acc[i];
    }
  }
}

extern "C" void kernel_launch(void* const* d_in, const int* in_sizes, int n_in,
                              void* d_out, int out_size, void* d_ws, size_t ws_size,
                              hipStream_t stream) {
  const float* queries = (const float*)d_in[0];
  const float* keys    = (const float*)d_in[1];
  const float* values  = (const float*)d_in[2];
  const int*   vlens   = (const int*)d_in[3];
  const float* Wq      = (const float*)d_in[4];
  const float* Wk      = (const float*)d_in[5];
  const float* wv      = (const float*)d_in[6];
  float* out = (float*)d_out;
  char* ws = (char*)d_ws;

  // workspace layout (bytes), ~17.3 MB
  unsigned short* wt_hi = (unsigned short*)(ws + 0);          // 256 KB
  unsigned short* wt_lo = (unsigned short*)(ws + 262144);     // 256 KB
  unsigned short* vt_hi = (unsigned short*)(ws + 524288);     //   2 MB
  unsigned short* vt_lo = (unsigned short*)(ws + 2621440);    //   2 MB
  float*          Rq    = (float*)(ws + 4718592);             //   4 MB [q][h]
  float*          RkT   = (float*)(ws + 8912896);             //   4 MB [b][h][k]
  float*          sc    = (float*)(ws + 13107200);            //   4 MB
  float*          wv2   = (float*)(ws + 17301504);            //   1 KB
  float*          Wsum  = (float*)(ws + 17302528);            //   4 B
  int*            cum   = (int*)(ws + 17302536);              //  68 B
  int*            ctr   = (int*)(ws + 17302604);              //   4 B (zeroed in P0)

  // Cooperative grid: all blocks must be co-resident. 2 blocks/CU by
  // __launch_bounds__(256,2) + 18.5 KB LDS; verify via occupancy query.
  static int nblk = 0;
  if (nblk == 0) {
    int per = 0;
    if (hipOccupancyMaxActiveBlocksPerMultiprocessor(&per, mega_kernel, 256, 0)
            != hipSuccess || per < 1)
      per = 1;
    if (per > 2) per = 2;
    int cus = 256;
    hipDeviceProp_t prop;
    int dev = 0;
    if (hipGetDevice(&dev) == hipSuccess &&
        hipGetDeviceProperties(&prop, dev) == hipSuccess &&
        prop.multiProcessorCount > 0)
      cus = prop.multiProcessorCount;
    nblk = per * cus;
    if (nblk < 1) nblk = 1;
  }

  void* args[] = {(void*)&queries, (void*)&keys, (void*)&values, (void*)&wv,
                  (void*)&vlens, (void*)&Wq, (void*)&Wk,
                  (void*)&wt_hi, (void*)&wt_lo, (void*)&vt_hi, (void*)&vt_lo,
                  (void*)&wv2, (void*)&Wsum, (void*)&cum, (void*)&ctr,
                  (void*)&Rq, (void*)&RkT, (void*)&sc, (void*)&out};
  hipLaunchCooperativeKernel((const void*)mega_kernel, dim3(nblk), dim3(256),
                             args, 0, stream);
}

// Round 6
// 146.036 us; speedup vs baseline: 2.2584x; 2.2584x over previous
//
#include <hip/hip_runtime.h>

// ---------- types ----------
using bf16x8 = __attribute__((ext_vector_type(8))) __bf16;
using f32x4  = __attribute__((ext_vector_type(4))) float;
using f32x2  = __attribute__((ext_vector_type(2))) float;
using us8    = __attribute__((ext_vector_type(8))) unsigned short;

#define TWO_LOG2E 2.8853900817779268f
#define LOG2E 1.4426950408889634f

__device__ __forceinline__ unsigned short f2bf(float x) {
  unsigned int u = __float_as_uint(x);
  u = (u + 0x7fffu + ((u >> 16) & 1u)) >> 16;   // RNE
  return (unsigned short)u;
}
__device__ __forceinline__ float bf2f(unsigned short h) {
  return __uint_as_float(((unsigned int)h) << 16);
}

// ---------- 1) tiled transpose+cast W/V + wv prologue + LPT job table ----------
__global__ __launch_bounds__(256) void tcast_kernel(
    const float* __restrict__ Wq, const float* __restrict__ Wk,
    const float* __restrict__ vals, const float* __restrict__ wv,
    const int* __restrict__ vlens,
    unsigned short* __restrict__ wt_hi, unsigned short* __restrict__ wt_lo,
    unsigned short* __restrict__ vt_hi, unsigned short* __restrict__ vt_lo,
    float* __restrict__ wv2, float* __restrict__ Wsum,
    unsigned short* __restrict__ jobs, int* __restrict__ ctr) {
  if (blockIdx.x == 0) {
    int t = threadIdx.x;
    wv2[t] = -2.0f * wv[t];                       // folded weight for scores
    if (t < 64) {
      float s = wv[t] + wv[t + 64] + wv[t + 128] + wv[t + 192];
#pragma unroll
      for (int off = 1; off < 64; off <<= 1) s += __shfl_xor(s, off, 64);
      if (t == 0) Wsum[0] = s;
    }
    if (t == 0) {                                 // LPT job table: heavy vl first
      ctr[0] = 0;
      int n = 0;
      for (int lvl = 4; lvl >= 1; --lvl)
        for (int b = 0; b < 16; ++b) {
          int kt = (vlens[b] + 63) >> 6;          // 1..4 k64-tiles
          if (kt == lvl)
            for (int q = 0; q < 32; ++q)
              jobs[n++] = (unsigned short)((b << 5) | q);   // (b, q8-strip)
        }
    }
  }
  __shared__ float tile[32][33];
  int m = blockIdx.x >> 6;                 // matrix 0..17
  int ts = blockIdx.x & 63;
  int R0 = (ts >> 3) << 5, C0 = (ts & 7) << 5;
  const float* src = (m == 0) ? Wq : (m == 1) ? Wk : (vals + ((m - 2) << 16));
  int r = threadIdx.x >> 3, c4 = (threadIdx.x & 7) << 2;
  float4 v = *(const float4*)(src + (R0 + r) * 256 + C0 + c4);
  tile[r][c4] = v.x; tile[r][c4 + 1] = v.y; tile[r][c4 + 2] = v.z; tile[r][c4 + 3] = v.w;
  __syncthreads();
  float o0 = tile[c4 + 0][r], o1 = tile[c4 + 1][r];
  float o2 = tile[c4 + 2][r], o3 = tile[c4 + 3][r];
  unsigned short h0 = f2bf(o0), h1 = f2bf(o1), h2 = f2bf(o2), h3 = f2bf(o3);
  int base = ((m < 2) ? (m << 16) : ((m - 2) << 16)) + (C0 + r) * 256 + R0 + c4;
  unsigned short* dh = (m < 2) ? wt_hi : vt_hi;
  unsigned short* dl = (m < 2) ? wt_lo : vt_lo;
  *(ushort4*)(dh + base) = make_ushort4(h0, h1, h2, h3);
  *(ushort4*)(dl + base) = make_ushort4(f2bf(o0 - bf2f(h0)), f2bf(o1 - bf2f(h1)),
                                        f2bf(o2 - bf2f(h2)), f2bf(o3 - bf2f(h3)));
}

// ---------- 2) projection GEMM + R = e^{2x} epilogue ----------
// Invalid k-tiles (rows >= valid_len) now ZERO-FILL RkT instead of skipping,
// so sav3 can read RkT unguarded (poison-free; masked at softmax anyway).
__global__ __launch_bounds__(256, 4) void proj_kernel(
    const float* __restrict__ q, const float* __restrict__ kk,
    const unsigned short* __restrict__ w_hi, const unsigned short* __restrict__ w_lo,
    const int* __restrict__ vlens, float* __restrict__ Rq, float* __restrict__ RkT) {
  int wave = threadIdx.x >> 6, lane = threadIdx.x & 63;
  int mt = (blockIdx.x << 1) + (wave & 1);   // m-tile 0..511
  int m0 = mt << 4;
  int g = mt >> 8;                           // 0: q rows / W_q, 1: k rows / W_k
  int r = lane & 15, qd = lane >> 4;
  int nbase = (blockIdx.y << 6) + ((wave >> 1) << 5);
  if (g) {
    int bb = (m0 >> 8) & 15;
    if ((m0 & 255) >= vlens[bb]) {           // dead tile: write zeros, no GEMM
      f32x4 z = {0.f, 0.f, 0.f, 0.f};
      int kloc = (m0 & 255) + qd * 4;
#pragma unroll
      for (int tI = 0; tI < 2; ++tI)
        *(f32x4*)(RkT + (bb << 16) + (nbase + (tI << 4) + r) * 256 + kloc) = z;
      return;
    }
  }
  int row = m0 + r;
  const float* A = (g == 0) ? (q + row * 256) : (kk + (row - 4096) * 256);
  int boff0 = (g << 16) + (nbase + r) * 256 + qd * 8;
  int boff1 = boff0 + (16 << 8);             // second n-tile (+16 rows)
  f32x4 acc0 = {0.f, 0.f, 0.f, 0.f}, acc1 = {0.f, 0.f, 0.f, 0.f};
#pragma unroll
  for (int kh = 0; kh < 2; ++kh) {
    bf16x8 ah[4], al[4];
#pragma unroll
    for (int s = 0; s < 4; ++s) {
      const float* p = A + qd * 8 + (kh * 4 + s) * 32;
      float4 f0 = *(const float4*)p;
      float4 f1 = *(const float4*)(p + 4);
      float fv[8] = {f0.x, f0.y, f0.z, f0.w, f1.x, f1.y, f1.z, f1.w};
#pragma unroll
      for (int j = 0; j < 8; ++j) {
        __bf16 h = (__bf16)fv[j];
        ah[s][j] = h;
        al[s][j] = (__bf16)(fv[j] - (float)h);
      }
    }
#pragma unroll
    for (int s = 0; s < 4; ++s) {
      int off = (kh * 4 + s) * 32;
      bf16x8 bh0 = *(const bf16x8*)(w_hi + boff0 + off);
      bf16x8 bl0 = *(const bf16x8*)(w_lo + boff0 + off);
      acc0 = __builtin_amdgcn_mfma_f32_16x16x32_bf16(ah[s], bh0, acc0, 0, 0, 0);
      acc0 = __builtin_amdgcn_mfma_f32_16x16x32_bf16(ah[s], bl0, acc0, 0, 0, 0);
      acc0 = __builtin_amdgcn_mfma_f32_16x16x32_bf16(al[s], bh0, acc0, 0, 0, 0);
      bf16x8 bh1 = *(const bf16x8*)(w_hi + boff1 + off);
      bf16x8 bl1 = *(const bf16x8*)(w_lo + boff1 + off);
      acc1 = __builtin_amdgcn_mfma_f32_16x16x32_bf16(ah[s], bh1, acc1, 0, 0, 0);
      acc1 = __builtin_amdgcn_mfma_f32_16x16x32_bf16(ah[s], bl1, acc1, 0, 0, 0);
      acc1 = __builtin_amdgcn_mfma_f32_16x16x32_bf16(al[s], bh1, acc1, 0, 0, 0);
    }
  }
#pragma unroll
  for (int tI = 0; tI < 2; ++tI) {
    f32x4 acc = tI ? acc1 : acc0;
    int n0 = nbase + (tI << 4);
    f32x4 ex;
#pragma unroll
    for (int i = 0; i < 4; ++i) {
      float l = acc[i] * TWO_LOG2E;                 // log2(e^{2x})
      l = fminf(fmaxf(l, -27.f), 27.f);
      ex[i] = __builtin_amdgcn_exp2f(l);
    }
    if (g == 0) {
#pragma unroll
      for (int i = 0; i < 4; ++i)
        Rq[(m0 + qd * 4 + i) * 256 + n0 + r] = ex[i];
    } else {
      int b = (m0 >> 8) & 15;
      int kloc = (m0 & 255) + qd * 4;               // contiguous in i
      *(f32x4*)(RkT + (b << 16) + (n0 + r) * 256 + kloc) = ex;
    }
  }
}

// ---------- 3) sav3: persistent work-steal fused scores+softmax+AV ----------
// 256 blocks x 512 thr (8 waves), stealing 512 LPT-ordered (b, q8) jobs.
// Scores: wave-per-row, lane=k, k-tiles proportional to vl (steal balances).
// v_rcp (trans pipe) replaces the 5-instr magic-Newton chain.
__global__ __launch_bounds__(512) void sav3_kernel(
    const float* __restrict__ Rq, const float* __restrict__ RkT,
    const float* __restrict__ wv2, const float* __restrict__ Wsum,
    const int* __restrict__ vlens, const unsigned short* __restrict__ jobs,
    int* __restrict__ ctr,
    const unsigned short* __restrict__ vhi, const unsigned short* __restrict__ vlo,
    float* __restrict__ out) {
  __shared__ __align__(16) float kT[256 * 68];     // [h][64k] padded
  __shared__ __align__(16) float rqs[8 * 260];     // [q8][h]
  __shared__ __align__(16) float scs[8 * 260];     // [q8][k]
  __shared__ __align__(16) unsigned short athi[16 * 264];  // rows 8..15 stay 0
  __shared__ float wv2s[256];
  __shared__ int s_item;
  const int t = threadIdx.x;
  const int w = t >> 6, lane = t & 63;
  const float wsum = Wsum[0];

  if (t < 256) wv2s[t] = wv2[t];
  for (int i = t; i < 8 * 264; i += 512) athi[8 * 264 + i] = 0;  // zero A top half

  for (;;) {
    __syncthreads();                    // prev job's AV reads done; init visible
    if (t == 0) s_item = atomicAdd(ctr, 1);
    __syncthreads();
    const int jid = s_item;
    if (jid >= 512) return;             // uniform exit
    const int jw = jobs[jid];
    const int b = jw >> 5, q0 = (jw & 31) << 3;
    const int qrow = (b << 8) + q0;
    const int vl = vlens[b];
    const int ktiles = (vl + 63) >> 6;

    { // stage rqs 8x256 (each thread one float4)
      int row = t >> 6, c = lane << 2;
      *(float4*)(rqs + row * 260 + c) = *(const float4*)(Rq + (qrow + row) * 256 + c);
    }
    for (int kt = 0; kt < ktiles; ++kt) {
      const int k0 = kt << 6;
      __syncthreads();                  // prev tile compute done / rqs staged
      { // stage kT [256h][64k]
        int h0 = t >> 2, kc = (t & 3) << 4;
#pragma unroll
        for (int p = 0; p < 2; ++p) {
          int h = h0 + (p << 7);
          const float* gk = RkT + (b << 16) + h * 256 + k0 + kc;
          *(float4*)(kT + h * 68 + kc)      = *(const float4*)gk;
          *(float4*)(kT + h * 68 + kc + 4)  = *(const float4*)(gk + 4);
          *(float4*)(kT + h * 68 + kc + 8)  = *(const float4*)(gk + 8);
          *(float4*)(kT + h * 68 + kc + 12) = *(const float4*)(gk + 12);
        }
      }
      __syncthreads();
      float a = 0.f;
#pragma unroll 4
      for (int h = 0; h < 256; ++h) {
        float qa = rqs[w * 260 + h];          // wave-uniform broadcast
        float wm = wv2s[h];                   // broadcast
        float rk = kT[h * 68 + lane];         // conflict-free (stride 68)
        float d = __builtin_fmaf(rk, qa, 1.0f);
        a = __builtin_fmaf(__builtin_amdgcn_rcpf(d), wm, a);
      }
      scs[w * 260 + k0 + lane] = a + wsum;
    }
    __syncthreads();                    // scores complete

    { // masked softmax: wave w owns row w; lane covers 4 cols
      int c0 = lane << 2;
      float4 x = *(const float4*)(scs + w * 260 + c0);
      float p[4] = {x.x, x.y, x.z, x.w};
#pragma unroll
      for (int i = 0; i < 4; ++i)
        if (c0 + i >= vl) p[i] = -1e6f;       // covers never-computed tiles too
      float mx = fmaxf(fmaxf(p[0], p[1]), fmaxf(p[2], p[3]));
#pragma unroll
      for (int off = 1; off < 64; off <<= 1) mx = fmaxf(mx, __shfl_xor(mx, off, 64));
      float sm = 0.f;
#pragma unroll
      for (int i = 0; i < 4; ++i) {
        p[i] = __builtin_amdgcn_exp2f((p[i] - mx) * LOG2E);   // masked -> 0
        sm += p[i];
      }
#pragma unroll
      for (int off = 1; off < 64; off <<= 1) sm += __shfl_xor(sm, off, 64);
      float rs = __builtin_amdgcn_rcpf(sm);
      ushort4 vh;
      vh.x = f2bf(p[0] * rs); vh.y = f2bf(p[1] * rs);
      vh.z = f2bf(p[2] * rs); vh.w = f2bf(p[3] * rs);
      *(ushort4*)(athi + w * 264 + c0) = vh;
    }
    __syncthreads();

    { // AV: wave w -> n in [32w, 32w+32); A rows 0..7 valid (8..15 zero)
      const int r = lane & 15, qd = lane >> 4;
      const int smax = (vl + 31) >> 5;
      const int nb = w << 5;
      const int boff = (b << 16) + (nb + r) * 256 + qd * 8;
      f32x4 acc0 = {0.f, 0.f, 0.f, 0.f}, acc1 = {0.f, 0.f, 0.f, 0.f};
      for (int s = 0; s < smax; ++s) {
        bf16x8 pa = *(const bf16x8*)(athi + r * 264 + qd * 8 + s * 32);
        bf16x8 bh0 = *(const bf16x8*)(vhi + boff + s * 32);
        bf16x8 bl0 = *(const bf16x8*)(vlo + boff + s * 32);
        acc0 = __builtin_amdgcn_mfma_f32_16x16x32_bf16(pa, bh0, acc0, 0, 0, 0);
        acc0 = __builtin_amdgcn_mfma_f32_16x16x32_bf16(pa, bl0, acc0, 0, 0, 0);
        bf16x8 bh1 = *(const bf16x8*)(vhi + boff + (16 << 8) + s * 32);
        bf16x8 bl1 = *(const bf16x8*)(vlo + boff + (16 << 8) + s * 32);
        acc1 = __builtin_amdgcn_mfma_f32_16x16x32_bf16(pa, bh1, acc1, 0, 0, 0);
        acc1 = __builtin_amdgcn_mfma_f32_16x16x32_bf16(pa, bl1, acc1, 0, 0, 0);
      }
      if (qd < 2) {                      // only D rows 0..7 are real q-rows
#pragma unroll
        for (int i = 0; i < 4; ++i) {
          out[(b << 16) + (q0 + qd * 4 + i) * 256 + nb + r]      = acc0[i];
          out[(b << 16) + (q0 + qd * 4 + i) * 256 + nb + 16 + r] = acc1[i];
        }
      }
    }
  }
}

extern "C" void kernel_launch(void* const* d_in, const int* in_sizes, int n_in,
                              void* d_out, int out_size, void* d_ws, size_t ws_size,
                              hipStream_t stream) {
  const float* queries = (const float*)d_in[0];
  const float* keys    = (const float*)d_in[1];
  const float* values  = (const float*)d_in[2];
  const int*   vlens   = (const int*)d_in[3];
  const float* Wq      = (const float*)d_in[4];
  const float* Wk      = (const float*)d_in[5];
  const float* wv      = (const float*)d_in[6];
  float* out = (float*)d_out;
  char* ws = (char*)d_ws;

  // workspace layout (bytes), ~13.3 MB
  unsigned short* wt_hi = (unsigned short*)(ws + 0);          // 256 KB
  unsigned short* wt_lo = (unsigned short*)(ws + 262144);     // 256 KB
  unsigned short* vt_hi = (unsigned short*)(ws + 524288);     //   2 MB
  unsigned short* vt_lo = (unsigned short*)(ws + 2621440);    //   2 MB
  float*          Rq    = (float*)(ws + 4718592);             //   4 MB [q][h]
  float*          RkT   = (float*)(ws + 8912896);             //   4 MB [b][h][k]
  float*          wv2   = (float*)(ws + 13107200);            //   1 KB
  float*          Wsum  = (float*)(ws + 13108224);            //   4 B
  unsigned short* jobs  = (unsigned short*)(ws + 13109248);   //   1 KB (512 jobs)
  int*            ctr   = (int*)(ws + 13110272);              //   4 B (zeroed by tcast)

  tcast_kernel<<<1152, 256, 0, stream>>>(Wq, Wk, values, wv, vlens,
                                         wt_hi, wt_lo, vt_hi, vt_lo, wv2, Wsum,
                                         jobs, ctr);
  proj_kernel<<<dim3(256, 4), 256, 0, stream>>>(queries, keys, wt_hi, wt_lo,
                                                vlens, Rq, RkT);
  sav3_kernel<<<256, 512, 0, stream>>>(Rq, RkT, wv2, Wsum, vlens, jobs, ctr,
                                       vt_hi, vt_lo, out);
}